// Round 4
// baseline (6919.955 us; speedup 1.0000x reference)
//
#include <hip/hip_runtime.h>

#define TT 512
#define VV 64

typedef _Float16 f16;
typedef f16 f16x8 __attribute__((ext_vector_type(8)));
typedef f16 f16x4 __attribute__((ext_vector_type(4)));
typedef f16 f16x2 __attribute__((ext_vector_type(2)));
typedef float f32x4v __attribute__((ext_vector_type(4)));

#define MFMA(A_,B_,C_) __builtin_amdgcn_mfma_f32_16x16x32_f16((A_),(B_),(C_),0,0,0)

// ws layout (bytes)
#define WS_IH1 0u
#define WS_HH1 49152u
#define WS_IH2 147456u
#define WS_HH2 245760u
#define WS_IH3 344064u
#define WS_HH3 442368u
#define WS_BIAS 540672u   // [3][256][32 f16] = 49152
// total 589824

__device__ __forceinline__ void barrier_lds(){ asm volatile("s_waitcnt lgkmcnt(0)\n\ts_barrier" ::: "memory"); }

// element offset (f16 units) of (k=d0.., col=b) in a B-frag buffer
__device__ __forceinline__ int fragOff16(int d0, int b){
  const int kt = d0 >> 5, qq = (d0 >> 3) & 3, j0 = d0 & 7;
  return (kt*64 + qq*16 + b)*8 + j0;
}
__device__ __forceinline__ void fragW4(f16x8* buf, int d0, int b, const float* h4){
  f16x4 v;
  #pragma unroll
  for (int e = 0; e < 4; ++e) v[e] = (f16)h4[e];
  *(f16x4*)((f16*)buf + fragOff16(d0, b)) = v;
}
__device__ __forceinline__ void fragW2(f16x8* buf, int v0, int b, float a0, float a1){
  f16x2 v; v[0] = (f16)a0; v[1] = (f16)a1;
  *(f16x2*)((f16*)buf + fragOff16(v0, b)) = v;
}
__device__ __forceinline__ float sigm(float v){ return 1.f/(1.f + __expf(-v)); }

// ---------------- k_init: pack weights/biases into ws ----------------
__global__ void k_init(const float* __restrict__ Wih1, const float* __restrict__ Whh1,
                       const float* __restrict__ Wih2, const float* __restrict__ Whh2,
                       const float* __restrict__ Wih3, const float* __restrict__ Whh3,
                       const float* __restrict__ bih1, const float* __restrict__ bhh1,
                       const float* __restrict__ bih2, const float* __restrict__ bhh2,
                       const float* __restrict__ bih3, const float* __restrict__ bhh3,
                       char* __restrict__ ws)
{
  const int n = blockIdx.x*256 + threadIdx.x;
  if (n < 33792){
    const float* W; int KF; unsigned off; int i = n;
    if (i < 3072){ W = Wih1; KF = 2; off = WS_IH1; }
    else {
      i -= 3072; const int mi = i/6144; i %= 6144;
      const float* Ws[5] = {Whh1, Wih2, Whh2, Wih3, Whh3};
      const unsigned offs[5] = {WS_HH1, WS_IH2, WS_HH2, WS_IH3, WS_HH3};
      W = Ws[mi]; off = offs[mi]; KF = 4;
    }
    const int l = i & 63; i >>= 6; const int kt = i % KF; const int m = i / KF;
    const int K = KF*32;
    const float* src = W + (size_t)(m*16 + (l & 15))*K + kt*32 + ((l >> 4) & 3)*8;
    f16x8 v;
    #pragma unroll
    for (int j = 0; j < 8; ++j) v[j] = (f16)src[j];
    *(f16x8*)(ws + off + ((size_t)(m*KF + kt)*64 + l)*16) = v;
  } else if (n < 34560){
    const int i = n - 33792; const int L = i >> 8, tid = i & 255;
    const float* bi = (L==0) ? bih1 : (L==1) ? bih2 : bih3;
    const float* bh = (L==0) ? bhh1 : (L==1) ? bhh2 : bhh3;
    const int w = tid >> 6, q = (tid >> 4) & 3;
    f16 out[32];
    #pragma unroll
    for (int G = 0; G < 2; ++G)
      #pragma unroll
      for (int e = 0; e < 4; ++e){
        const int d = (w + 4*G)*16 + 4*q + e;
        out[G*16 + 0  + e] = (f16)(bi[d] + bh[d]);
        out[G*16 + 4  + e] = (f16)(bi[128+d] + bh[128+d]);
        out[G*16 + 8  + e] = (f16)bi[256+d];
        out[G*16 + 12 + e] = (f16)bh[256+d];
      }
    #pragma unroll
    for (int k = 0; k < 4; ++k)
      *(f16x8*)(ws + WS_BIAS + (size_t)(L*256 + tid)*64 + k*16) = *(f16x8*)&out[k*8];
  }
}

// ---------------- k_main: fused 3-layer GRU-D, one block per 8 batches ----------------
__launch_bounds__(256, 1)
__global__ void k_main(const float* __restrict__ x,  const float* __restrict__ dd,
                       const float* __restrict__ m1,
                       const float* __restrict__ h01, const float* __restrict__ h02,
                       const float* __restrict__ h03,
                       const float* __restrict__ Wdx_, const float* __restrict__ bdx_,
                       const float* __restrict__ Wdh_, const float* __restrict__ bdh_,
                       const float* __restrict__ Wout, const float* __restrict__ bout,
                       float* __restrict__ y, const char* __restrict__ ws)
{
  __shared__ f16x8 bufA[256];     // γh1
  __shared__ f16x8 bufB[256];     // h1f / h2f
  __shared__ f16x8 bufC[256];     // γh2 / γh3
  __shared__ f16x8 bufX[128];     // x1
  __shared__ float headBuf[4][8][4];
  __shared__ f16   sWout[128][4];

  const int tid = threadIdx.x, w = tid >> 6, lane = tid & 63;
  const int q = lane >> 4, r = lane & 15;
  const int b0 = blockIdx.x * 8;

  if (tid < 128){
    #pragma unroll
    for (int c = 0; c < 4; ++c) sWout[tid][c] = (f16)Wout[c*128 + tid];
  }

  // static recurrent weights (Whh1..3) from ws frags
  f16x8 Ahh[3][2][3][4];
  {
    const unsigned hhOff[3] = {WS_HH1, WS_HH2, WS_HH3};
    #pragma unroll
    for (int L = 0; L < 3; ++L)
      #pragma unroll
      for (int G = 0; G < 2; ++G)
        #pragma unroll
        for (int g = 0; g < 3; ++g){
          const int m = g*8 + w + 4*G;
          #pragma unroll
          for (int kt = 0; kt < 4; ++kt)
            Ahh[L][G][g][kt] = *(const f16x8*)(ws + hhOff[L] + ((size_t)(m*4 + kt)*64 + lane)*16);
        }
  }
  // decay params (own d positions)
  float WdhL[2][4], bdhL[2][4];
  #pragma unroll
  for (int G = 0; G < 2; ++G)
    #pragma unroll
    for (int e = 0; e < 4; ++e){
      const int d = (w + 4*G)*16 + 4*q + e;
      WdhL[G][e] = Wdh_[d]; bdhL[G][e] = bdh_[d];
    }
  // x-path: thread handles (bx, v0..v0+1)
  const int bx = tid >> 5, v0 = (tid & 31)*2;
  const float wdx0 = Wdx_[v0], wdx1 = Wdx_[v0+1];
  const float bdx0 = bdx_[v0], bdx1 = bdx_[v0+1];

  // h state (C-layout), zero for padded batches r>=8
  float hS[3][2][4];
  {
    const float* h0s[3] = {h01, h02, h03};
    #pragma unroll
    for (int L = 0; L < 3; ++L)
      #pragma unroll
      for (int G = 0; G < 2; ++G){
        const int d = (w + 4*G)*16 + 4*q;
        if (r < 8){
          const float4 a = *(const float4*)(h0s[L] + (size_t)(b0 + r)*128 + d);
          hS[L][G][0]=a.x; hS[L][G][1]=a.y; hS[L][G][2]=a.z; hS[L][G][3]=a.w;
        } else {
          hS[L][G][0]=0.f; hS[L][G][1]=0.f; hS[L][G][2]=0.f; hS[L][G][3]=0.f;
        }
      }
  }
  float bo[4];
  if (tid < 8){
    #pragma unroll
    for (int c = 0; c < 4; ++c) bo[c] = bout[c];
  }

  // x/m/d pipeline
  float xc0, xc1, x00, x01, xp0 = 0.f, xp1 = 0.f;
  float mc0 = 0.f, mc1 = 0.f, mn0, mn1, xn0, xn1;
  float dxC = 0.f, dhC = 0.f, dxN, dhN;
  {
    const float* px = x + ((size_t)(b0 + bx)*TT + 0)*VV + v0;
    xc0 = px[0]; xc1 = px[1]; x00 = xc0; x01 = xc1;
    const float* pn = x + ((size_t)(b0 + bx)*TT + 1)*VV + v0;
    xn0 = pn[0]; xn1 = pn[1];
    const float* pm = m1 + ((size_t)(b0 + bx)*TT + 1)*VV + v0;
    mn0 = pm[0]; mn1 = pm[1];
    dxN = dd[(size_t)(b0 + bx)*TT + 1];
    dhN = (r < 8) ? dd[(size_t)(b0 + r)*TT + 1] : 0.f;
  }

  // first streamed Wih1
  f16x8 Ai1[2][3][2];
  #pragma unroll
  for (int G = 0; G < 2; ++G)
    #pragma unroll
    for (int g = 0; g < 3; ++g){
      const int m = g*8 + w + 4*G;
      #pragma unroll
      for (int kt = 0; kt < 2; ++kt)
        Ai1[G][g][kt] = *(const f16x8*)(ws + WS_IH1 + ((size_t)(m*2 + kt)*64 + lane)*16);
    }
  f16x8 Ai2[2][3][4], Ai3[2][3][4];

  __syncthreads();

  float g8[2][4];

  for (int t = 0; t < TT; ++t){
    // ============ B0: head partials, decay, pack γh1 + x1 ============
    if (t >= 1){
      // head partial from fresh h3(t-1), BEFORE decay
      float p[4] = {0.f, 0.f, 0.f, 0.f};
      #pragma unroll
      for (int G = 0; G < 2; ++G)
        #pragma unroll
        for (int e = 0; e < 4; ++e){
          const int d = (w + 4*G)*16 + 4*q + e;
          const float hv = hS[2][G][e];
          #pragma unroll
          for (int c = 0; c < 4; ++c) p[c] += hv * (float)sWout[d][c];
        }
      #pragma unroll
      for (int c = 0; c < 4; ++c){
        p[c] += __shfl_xor(p[c], 16);
        p[c] += __shfl_xor(p[c], 32);
      }
      if (q == 0 && r < 8){
        float4 o; o.x = p[0]; o.y = p[1]; o.z = p[2]; o.w = p[3];
        *(float4*)&headBuf[w][r][0] = o;
      }
      // decay factors (shared across layers)
      #pragma unroll
      for (int G = 0; G < 2; ++G)
        #pragma unroll
        for (int e = 0; e < 4; ++e)
          g8[G][e] = __expf(-fmaxf(dhC*WdhL[G][e] + bdhL[G][e], 0.f));
    } else {
      #pragma unroll
      for (int G = 0; G < 2; ++G)
        #pragma unroll
        for (int e = 0; e < 4; ++e) g8[G][e] = 1.f;
    }
    #pragma unroll
    for (int G = 0; G < 2; ++G){
      #pragma unroll
      for (int e = 0; e < 4; ++e) hS[0][G][e] *= g8[G][e];
      fragW4(bufA, (w + 4*G)*16 + 4*q, r, hS[0][G]);
    }
    // x1 imputation
    {
      float xi0, xi1;
      if (t == 0){ xi0 = xc0; xi1 = xc1; }
      else {
        const float gx0 = __expf(-fmaxf(dxC*wdx0 + bdx0, 0.f));
        const float gx1 = __expf(-fmaxf(dxC*wdx1 + bdx1, 0.f));
        xi0 = (xp0*gx0 + (1.f-gx0)*x00)*(1.f-mc0) + mc0*xc0;
        xi1 = (xp1*gx1 + (1.f-gx1)*x01)*(1.f-mc1) + mc1*xc1;
      }
      fragW2(bufX, v0, bx, xi0, xi1);
    }
    barrier_lds();  // B0

    // wave0: finish head for t-1
    if (t >= 1 && tid < 8){
      float l0 = bo[0], l1 = bo[1], l2 = bo[2], l3 = bo[3];
      #pragma unroll
      for (int wv = 0; wv < 4; ++wv){
        const float4 o = *(const float4*)&headBuf[wv][tid][0];
        l0 += o.x; l1 += o.y; l2 += o.z; l3 += o.w;
      }
      const float mx = fmaxf(fmaxf(l0,l1), fmaxf(l2,l3));
      const float e0 = __expf(l0-mx), e1 = __expf(l1-mx), e2 = __expf(l2-mx), e3 = __expf(l3-mx);
      const float inv = 1.f/(e0+e1+e2+e3);
      float4 o; o.x = e0*inv; o.y = e1*inv; o.z = e2*inv; o.w = e3*inv;
      *(float4*)(y + ((size_t)(b0 + tid)*TT + (t-1))*4) = o;
    }

    // ============ P1 ============
    {
      f16x8 bg[4], bxr[2], bb[4];
      #pragma unroll
      for (int k = 0; k < 4; ++k) bb[k] = *(const f16x8*)(ws + WS_BIAS + (size_t)(0*256 + tid)*64 + k*16);
      #pragma unroll
      for (int kt = 0; kt < 4; ++kt) bg[kt] = bufA[kt*64 + lane];
      bxr[0] = bufX[lane]; bxr[1] = bufX[64 + lane];
      f32x4v aR[2], aZ[2], aNh[2], aNi[2];
      #pragma unroll
      for (int G = 0; G < 2; ++G){ aR[G]=(f32x4v){0,0,0,0}; aZ[G]=(f32x4v){0,0,0,0}; aNh[G]=(f32x4v){0,0,0,0}; aNi[G]=(f32x4v){0,0,0,0}; }
      #pragma unroll
      for (int kt = 0; kt < 4; ++kt)
        #pragma unroll
        for (int G = 0; G < 2; ++G){
          aR[G]  = MFMA(Ahh[0][G][0][kt], bg[kt], aR[G]);
          aZ[G]  = MFMA(Ahh[0][G][1][kt], bg[kt], aZ[G]);
          aNh[G] = MFMA(Ahh[0][G][2][kt], bg[kt], aNh[G]);
        }
      #pragma unroll
      for (int kt = 0; kt < 2; ++kt)
        #pragma unroll
        for (int G = 0; G < 2; ++G){
          aR[G]  = MFMA(Ai1[G][0][kt], bxr[kt], aR[G]);
          aZ[G]  = MFMA(Ai1[G][1][kt], bxr[kt], aZ[G]);
          aNi[G] = MFMA(Ai1[G][2][kt], bxr[kt], aNi[G]);
        }
      // gates1
      #pragma unroll
      for (int G = 0; G < 2; ++G)
        #pragma unroll
        for (int e = 0; e < 4; ++e){
          const float bR = (float)bb[2*G][e],   bZ = (float)bb[2*G][4+e];
          const float bI = (float)bb[2*G+1][e], bH = (float)bb[2*G+1][4+e];
          const float rr = sigm(aR[G][e] + bR);
          const float zz = sigm(aZ[G][e] + bZ);
          const float nv = aNi[G][e] + bI + rr*(aNh[G][e] + bH);
          const float nn = 1.f - 2.f/(1.f + __expf(2.f*nv));
          hS[0][G][e] = (1.f - zz)*nn + zz*hS[0][G][e];
        }
    }
    // issue streamed Wih2
    #pragma unroll
    for (int G = 0; G < 2; ++G)
      #pragma unroll
      for (int g = 0; g < 3; ++g){
        const int m = g*8 + w + 4*G;
        #pragma unroll
        for (int kt = 0; kt < 4; ++kt)
          Ai2[G][g][kt] = *(const f16x8*)(ws + WS_IH2 + ((size_t)(m*4 + kt)*64 + lane)*16);
      }
    barrier_lds();  // B1a
    #pragma unroll
    for (int G = 0; G < 2; ++G){
      #pragma unroll
      for (int e = 0; e < 4; ++e) hS[1][G][e] *= g8[G][e];
      fragW4(bufC, (w + 4*G)*16 + 4*q, r, hS[1][G]);   // γh2
      fragW4(bufB, (w + 4*G)*16 + 4*q, r, hS[0][G]);   // h1 fresh
    }
    barrier_lds();  // B1b

    // ============ P2 ============
    {
      f16x8 bg[4], bi4[4], bb[4];
      #pragma unroll
      for (int k = 0; k < 4; ++k) bb[k] = *(const f16x8*)(ws + WS_BIAS + (size_t)(1*256 + tid)*64 + k*16);
      #pragma unroll
      for (int kt = 0; kt < 4; ++kt){ bg[kt] = bufC[kt*64 + lane]; bi4[kt] = bufB[kt*64 + lane]; }
      f32x4v aR[2], aZ[2], aNh[2], aNi[2];
      #pragma unroll
      for (int G = 0; G < 2; ++G){ aR[G]=(f32x4v){0,0,0,0}; aZ[G]=(f32x4v){0,0,0,0}; aNh[G]=(f32x4v){0,0,0,0}; aNi[G]=(f32x4v){0,0,0,0}; }
      #pragma unroll
      for (int kt = 0; kt < 4; ++kt)
        #pragma unroll
        for (int G = 0; G < 2; ++G){
          aR[G]  = MFMA(Ahh[1][G][0][kt], bg[kt], aR[G]);
          aZ[G]  = MFMA(Ahh[1][G][1][kt], bg[kt], aZ[G]);
          aNh[G] = MFMA(Ahh[1][G][2][kt], bg[kt], aNh[G]);
        }
      #pragma unroll
      for (int kt = 0; kt < 4; ++kt)
        #pragma unroll
        for (int G = 0; G < 2; ++G){
          aR[G]  = MFMA(Ai2[G][0][kt], bi4[kt], aR[G]);
          aZ[G]  = MFMA(Ai2[G][1][kt], bi4[kt], aZ[G]);
          aNi[G] = MFMA(Ai2[G][2][kt], bi4[kt], aNi[G]);
        }
      #pragma unroll
      for (int G = 0; G < 2; ++G)
        #pragma unroll
        for (int e = 0; e < 4; ++e){
          const float bR = (float)bb[2*G][e],   bZ = (float)bb[2*G][4+e];
          const float bI = (float)bb[2*G+1][e], bH = (float)bb[2*G+1][4+e];
          const float rr = sigm(aR[G][e] + bR);
          const float zz = sigm(aZ[G][e] + bZ);
          const float nv = aNi[G][e] + bI + rr*(aNh[G][e] + bH);
          const float nn = 1.f - 2.f/(1.f + __expf(2.f*nv));
          hS[1][G][e] = (1.f - zz)*nn + zz*hS[1][G][e];
        }
    }
    // issue streamed Wih3
    #pragma unroll
    for (int G = 0; G < 2; ++G)
      #pragma unroll
      for (int g = 0; g < 3; ++g){
        const int m = g*8 + w + 4*G;
        #pragma unroll
        for (int kt = 0; kt < 4; ++kt)
          Ai3[G][g][kt] = *(const f16x8*)(ws + WS_IH3 + ((size_t)(m*4 + kt)*64 + lane)*16);
      }
    barrier_lds();  // B2a
    #pragma unroll
    for (int G = 0; G < 2; ++G){
      #pragma unroll
      for (int e = 0; e < 4; ++e) hS[2][G][e] *= g8[G][e];
      fragW4(bufC, (w + 4*G)*16 + 4*q, r, hS[2][G]);   // γh3
      fragW4(bufB, (w + 4*G)*16 + 4*q, r, hS[1][G]);   // h2 fresh
    }
    barrier_lds();  // B2b

    // ============ P3 ============
    {
      f16x8 bg[4], bi4[4], bb[4];
      #pragma unroll
      for (int k = 0; k < 4; ++k) bb[k] = *(const f16x8*)(ws + WS_BIAS + (size_t)(2*256 + tid)*64 + k*16);
      #pragma unroll
      for (int kt = 0; kt < 4; ++kt){ bg[kt] = bufC[kt*64 + lane]; bi4[kt] = bufB[kt*64 + lane]; }
      f32x4v aR[2], aZ[2], aNh[2], aNi[2];
      #pragma unroll
      for (int G = 0; G < 2; ++G){ aR[G]=(f32x4v){0,0,0,0}; aZ[G]=(f32x4v){0,0,0,0}; aNh[G]=(f32x4v){0,0,0,0}; aNi[G]=(f32x4v){0,0,0,0}; }
      #pragma unroll
      for (int kt = 0; kt < 4; ++kt)
        #pragma unroll
        for (int G = 0; G < 2; ++G){
          aR[G]  = MFMA(Ahh[2][G][0][kt], bg[kt], aR[G]);
          aZ[G]  = MFMA(Ahh[2][G][1][kt], bg[kt], aZ[G]);
          aNh[G] = MFMA(Ahh[2][G][2][kt], bg[kt], aNh[G]);
        }
      #pragma unroll
      for (int kt = 0; kt < 4; ++kt)
        #pragma unroll
        for (int G = 0; G < 2; ++G){
          aR[G]  = MFMA(Ai3[G][0][kt], bi4[kt], aR[G]);
          aZ[G]  = MFMA(Ai3[G][1][kt], bi4[kt], aZ[G]);
          aNi[G] = MFMA(Ai3[G][2][kt], bi4[kt], aNi[G]);
        }
      #pragma unroll
      for (int G = 0; G < 2; ++G)
        #pragma unroll
        for (int e = 0; e < 4; ++e){
          const float bR = (float)bb[2*G][e],   bZ = (float)bb[2*G][4+e];
          const float bI = (float)bb[2*G+1][e], bH = (float)bb[2*G+1][4+e];
          const float rr = sigm(aR[G][e] + bR);
          const float zz = sigm(aZ[G][e] + bZ);
          const float nv = aNi[G][e] + bI + rr*(aNh[G][e] + bH);
          const float nn = 1.f - 2.f/(1.f + __expf(2.f*nv));
          hS[2][G][e] = (1.f - zz)*nn + zz*hS[2][G][e];
        }
    }

    // issue next step's Wih1 + rotate/prefetch x,m,d
    #pragma unroll
    for (int G = 0; G < 2; ++G)
      #pragma unroll
      for (int g = 0; g < 3; ++g){
        const int m = g*8 + w + 4*G;
        #pragma unroll
        for (int kt = 0; kt < 2; ++kt)
          Ai1[G][g][kt] = *(const f16x8*)(ws + WS_IH1 + ((size_t)(m*2 + kt)*64 + lane)*16);
      }
    xp0 = xc0; xp1 = xc1; xc0 = xn0; xc1 = xn1;
    mc0 = mn0; mc1 = mn1; dxC = dxN; dhC = dhN;
    {
      const int tp = (t + 2 < TT) ? (t + 2) : (TT - 1);
      const float* pn = x + ((size_t)(b0 + bx)*TT + tp)*VV + v0;
      xn0 = pn[0]; xn1 = pn[1];
      const float* pm = m1 + ((size_t)(b0 + bx)*TT + tp)*VV + v0;
      mn0 = pm[0]; mn1 = pm[1];
      dxN = dd[(size_t)(b0 + bx)*TT + tp];
      dhN = (r < 8) ? dd[(size_t)(b0 + r)*TT + tp] : 0.f;
    }
  }

  // ============ epilogue: y[TT-1] from fresh h3 ============
  {
    float p[4] = {0.f, 0.f, 0.f, 0.f};
    #pragma unroll
    for (int G = 0; G < 2; ++G)
      #pragma unroll
      for (int e = 0; e < 4; ++e){
        const int d = (w + 4*G)*16 + 4*q + e;
        const float hv = hS[2][G][e];
        #pragma unroll
        for (int c = 0; c < 4; ++c) p[c] += hv * (float)sWout[d][c];
      }
    #pragma unroll
    for (int c = 0; c < 4; ++c){
      p[c] += __shfl_xor(p[c], 16);
      p[c] += __shfl_xor(p[c], 32);
    }
    if (q == 0 && r < 8){
      float4 o; o.x = p[0]; o.y = p[1]; o.z = p[2]; o.w = p[3];
      *(float4*)&headBuf[w][r][0] = o;
    }
    barrier_lds();
    if (tid < 8){
      float l0 = bo[0], l1 = bo[1], l2 = bo[2], l3 = bo[3];
      #pragma unroll
      for (int wv = 0; wv < 4; ++wv){
        const float4 o = *(const float4*)&headBuf[wv][tid][0];
        l0 += o.x; l1 += o.y; l2 += o.z; l3 += o.w;
      }
      const float mx = fmaxf(fmaxf(l0,l1), fmaxf(l2,l3));
      const float e0 = __expf(l0-mx), e1 = __expf(l1-mx), e2 = __expf(l2-mx), e3 = __expf(l3-mx);
      const float inv = 1.f/(e0+e1+e2+e3);
      float4 o; o.x = e0*inv; o.y = e1*inv; o.z = e2*inv; o.w = e3*inv;
      *(float4*)(y + ((size_t)(b0 + tid)*TT + (TT-1))*4) = o;
    }
  }
}

extern "C" void kernel_launch(void* const* d_in, const int* in_sizes, int n_in,
                              void* d_out, int out_size, void* d_ws, size_t ws_size,
                              hipStream_t stream) {
  (void)in_sizes; (void)n_in; (void)out_size; (void)ws_size;
  char* ws = (char*)d_ws;
  k_init<<<dim3(135), dim3(256), 0, stream>>>(
      (const float*)d_in[6],  (const float*)d_in[7],   // Wih1, Whh1
      (const float*)d_in[10], (const float*)d_in[11],  // Wih2, Whh2
      (const float*)d_in[14], (const float*)d_in[15],  // Wih3, Whh3
      (const float*)d_in[8],  (const float*)d_in[9],   // bih1, bhh1
      (const float*)d_in[12], (const float*)d_in[13],
      (const float*)d_in[16], (const float*)d_in[17],
      ws);
  k_main<<<dim3(64), dim3(256), 0, stream>>>(
      (const float*)d_in[0],  (const float*)d_in[1],  (const float*)d_in[2],   // x, d, m1
      (const float*)d_in[3],  (const float*)d_in[4],  (const float*)d_in[5],   // h0_1..3
      (const float*)d_in[20], (const float*)d_in[21],                          // W_dx, b_dx
      (const float*)d_in[22], (const float*)d_in[23],                          // W_dh, b_dh
      (const float*)d_in[18], (const float*)d_in[19],                          // W_out, b_out
      (float*)d_out, ws);
}

// Round 5
// 6034.236 us; speedup vs baseline: 1.1468x; 1.1468x over previous
//
#include <hip/hip_runtime.h>

#define TT 512
#define VV 64

typedef _Float16 f16;
typedef f16 f16x8 __attribute__((ext_vector_type(8)));
typedef f16 f16x4 __attribute__((ext_vector_type(4)));
typedef float f32x4v __attribute__((ext_vector_type(4)));

#define MFMA(A_,B_,C_) __builtin_amdgcn_mfma_f32_16x16x32_f16((A_),(B_),(C_),0,0,0)

// ws layout (bytes) — f16 MFMA A-fragments packed by k_init
#define WS_IH1 0u
#define WS_HH1 49152u
#define WS_IH2 147456u
#define WS_HH2 245760u
#define WS_IH3 344064u
#define WS_HH3 442368u
// total 540672

__device__ __forceinline__ void barrier_lds(){ asm volatile("s_waitcnt lgkmcnt(0)\n\ts_barrier" ::: "memory"); }

// element offset (f16 units) of (k=d0.., col=b) in a B-frag buffer
__device__ __forceinline__ int fragOff16(int d0, int b){
  const int kt = d0 >> 5, qq = (d0 >> 3) & 3, j0 = d0 & 7;
  return (kt*64 + qq*16 + b)*8 + j0;
}
__device__ __forceinline__ void fragW4(f16x8* buf, int d0, int b, const float* h4){
  f16x4 v;
  #pragma unroll
  for (int e = 0; e < 4; ++e) v[e] = (f16)h4[e];
  *(f16x4*)((f16*)buf + fragOff16(d0, b)) = v;
}
__device__ __forceinline__ float sigm(float v){ return 1.f/(1.f + __expf(-v)); }
__device__ __forceinline__ float4 ld4(const float* p){ return *(const float4*)p; }

__device__ __forceinline__ f16x8 ldws4(const char* ws, unsigned off, int m, int kt, int lane){
  return *(const f16x8*)(ws + off + (((size_t)(m*4 + kt))*64 + lane)*16);
}
__device__ __forceinline__ f16x8 ldws2(const char* ws, unsigned off, int m, int kt, int lane){
  return *(const f16x8*)(ws + off + (((size_t)(m*2 + kt))*64 + lane)*16);
}

// gates with biases pre-folded into accumulators
__device__ __forceinline__ void gates4(const f32x4v aR, const f32x4v aZ,
                                       const f32x4v aNi, const f32x4v aNh, float* hp){
  #pragma unroll
  for (int e = 0; e < 4; ++e){
    const float rr = sigm(aR[e]);
    const float zz = sigm(aZ[e]);
    const float nv = aNi[e] + rr*aNh[e];
    const float nn = 1.f - 2.f/(1.f + __expf(2.f*nv));
    hp[e] = (1.f - zz)*nn + zz*hp[e];
  }
}

// ---------------- k_init: pack weights into f16 A-fragments ----------------
__global__ void k_init(const float* __restrict__ Wih1, const float* __restrict__ Whh1,
                       const float* __restrict__ Wih2, const float* __restrict__ Whh2,
                       const float* __restrict__ Wih3, const float* __restrict__ Whh3,
                       char* __restrict__ ws)
{
  const int n = blockIdx.x*256 + threadIdx.x;
  if (n >= 33792) return;
  const float* W; int KF; unsigned off; int i = n;
  if (i < 3072){ W = Wih1; KF = 2; off = WS_IH1; }
  else {
    i -= 3072; const int mi = i/6144; i %= 6144;
    const float* Ws[5] = {Whh1, Wih2, Whh2, Wih3, Whh3};
    const unsigned offs[5] = {WS_HH1, WS_IH2, WS_HH2, WS_IH3, WS_HH3};
    W = Ws[mi]; off = offs[mi]; KF = 4;
  }
  const int l = i & 63; i >>= 6; const int kt = i % KF; const int m = i / KF;
  const int K = KF*32;
  const float* src = W + (size_t)(m*16 + (l & 15))*K + kt*32 + ((l >> 4) & 3)*8;
  f16x8 v;
  #pragma unroll
  for (int j = 0; j < 8; ++j) v[j] = (f16)src[j];
  *(f16x8*)(ws + off + ((size_t)(m*KF + kt)*64 + l)*16) = v;
}

// ---------------- k_main: fused 3-layer GRU-D, one block per 16 batches ----------------
__launch_bounds__(256, 1)
__global__ void k_main(const float* __restrict__ x,  const float* __restrict__ dd,
                       const float* __restrict__ m1,
                       const float* __restrict__ h01, const float* __restrict__ h02,
                       const float* __restrict__ h03,
                       const float* __restrict__ bih1, const float* __restrict__ bhh1,
                       const float* __restrict__ bih2, const float* __restrict__ bhh2,
                       const float* __restrict__ bih3, const float* __restrict__ bhh3,
                       const float* __restrict__ Wdx_, const float* __restrict__ bdx_,
                       const float* __restrict__ Wdh_, const float* __restrict__ bdh_,
                       const float* __restrict__ Wout, const float* __restrict__ bout,
                       float* __restrict__ y, const char* __restrict__ ws)
{
  __shared__ f16x8 bufA[256];   // γh1
  __shared__ f16x8 bufB[256];   // γh2
  __shared__ f16x8 bufC[256];   // γh3
  __shared__ f16x8 bufD[256];   // h1 fresh
  __shared__ f16x8 bufE[256];   // h2 fresh
  __shared__ f16x8 bufX[128];   // x1
  __shared__ float sBias[3][4][128];   // [L][r,z,bI,bH][d]
  __shared__ float sWdh[128], sbdh[128];
  __shared__ f16   sWout[128][4];
  __shared__ float headBuf[4][16][4];

  const int tid = threadIdx.x, w = tid >> 6, lane = tid & 63;
  const int q = lane >> 4, r = lane & 15;
  const int b0 = blockIdx.x * 16;

  if (tid < 128){
    const float* bis[3] = {bih1, bih2, bih3};
    const float* bhs[3] = {bhh1, bhh2, bhh3};
    #pragma unroll
    for (int L = 0; L < 3; ++L){
      sBias[L][0][tid] = bis[L][tid]       + bhs[L][tid];
      sBias[L][1][tid] = bis[L][128 + tid] + bhs[L][128 + tid];
      sBias[L][2][tid] = bis[L][256 + tid];
      sBias[L][3][tid] = bhs[L][256 + tid];
    }
    sWdh[tid] = Wdh_[tid]; sbdh[tid] = bdh_[tid];
    #pragma unroll
    for (int c = 0; c < 4; ++c) sWout[tid][c] = (f16)Wout[c*128 + tid];
  }
  float bo[4];
  if (tid < 16){
    #pragma unroll
    for (int c = 0; c < 4; ++c) bo[c] = bout[c];
  }

  // static recurrent weights (cold, MFMA-A-only)
  f16x8 Ahh[3][2][3][4];
  {
    const unsigned hhOff[3] = {WS_HH1, WS_HH2, WS_HH3};
    #pragma unroll
    for (int L = 0; L < 3; ++L)
      #pragma unroll
      for (int G = 0; G < 2; ++G)
        #pragma unroll
        for (int g = 0; g < 3; ++g){
          const int m = g*8 + w + 4*G;
          #pragma unroll
          for (int kt = 0; kt < 4; ++kt)
            Ahh[L][G][g][kt] = ldws4(ws, hhOff[L], m, kt, lane);
        }
  }

  // h state (C-layout: col=batch=r, row=d)
  float hS[3][2][4];
  {
    const float* h0s[3] = {h01, h02, h03};
    #pragma unroll
    for (int L = 0; L < 3; ++L)
      #pragma unroll
      for (int G = 0; G < 2; ++G){
        const int d = (w + 4*G)*16 + 4*q;
        const float4 a = ld4(h0s[L] + (size_t)(b0 + r)*128 + d);
        hS[L][G][0]=a.x; hS[L][G][1]=a.y; hS[L][G][2]=a.z; hS[L][G][3]=a.w;
      }
  }

  // x-path: thread handles (batch bx, v0..v0+3)
  const int bx = tid >> 4, v0 = (tid & 15)*4;
  float Wdx4[4], bdx4[4];
  #pragma unroll
  for (int e = 0; e < 4; ++e){ Wdx4[e] = Wdx_[v0+e]; bdx4[e] = bdx_[v0+e]; }

  float4 xC = ld4(x + ((size_t)(b0 + bx)*TT + 0)*VV + v0);
  const float4 x0v = xC;
  float4 xN = ld4(x  + ((size_t)(b0 + bx)*TT + 1)*VV + v0);
  float4 mN = ld4(m1 + ((size_t)(b0 + bx)*TT + 1)*VV + v0);
  float dxN = dd[(size_t)(b0 + bx)*TT + 1];
  float dhN = dd[(size_t)(b0 + r)*TT + 1];
  float4 xP = xC, mC = mN;
  float dxC = dxN, dhC = dhN;

  // streamed input-side weights
  f16x8 Ai1[2][3][2];          // ih1 (live P3-end .. P1)
  #pragma unroll
  for (int G = 0; G < 2; ++G)
    #pragma unroll
    for (int g = 0; g < 3; ++g)
      #pragma unroll
      for (int kt = 0; kt < 2; ++kt)
        Ai1[G][g][kt] = ldws2(ws, WS_IH1, g*8 + w + 4*G, kt, lane);
  f16x8 AiA[3][4], AiB[3][4];  // rotating 48-reg chunks

  __syncthreads();

  for (int t = 0; t < TT; ++t){
    // ================= B0: head partial, decay, pack frags =================
    if (t >= 1){
      // head partial from fresh h3(t-1), BEFORE decay
      float p[4] = {0.f, 0.f, 0.f, 0.f};
      #pragma unroll
      for (int G = 0; G < 2; ++G)
        #pragma unroll
        for (int e = 0; e < 4; ++e){
          const int d = (w + 4*G)*16 + 4*q + e;
          const float hv = hS[2][G][e];
          #pragma unroll
          for (int c = 0; c < 4; ++c) p[c] += hv * (float)sWout[d][c];
        }
      #pragma unroll
      for (int c = 0; c < 4; ++c){
        p[c] += __shfl_xor(p[c], 16);
        p[c] += __shfl_xor(p[c], 32);
      }
      if (q == 0){
        float4 o; o.x = p[0]; o.y = p[1]; o.z = p[2]; o.w = p[3];
        *(float4*)&headBuf[w][r][0] = o;
      }
      // decay (params from LDS — transient regs only)
      #pragma unroll
      for (int G = 0; G < 2; ++G){
        const int d = (w + 4*G)*16 + 4*q;
        const float4 wv = *(const float4*)&sWdh[d];
        const float4 bv = *(const float4*)&sbdh[d];
        float g4[4];
        g4[0] = __expf(-fmaxf(dhC*wv.x + bv.x, 0.f));
        g4[1] = __expf(-fmaxf(dhC*wv.y + bv.y, 0.f));
        g4[2] = __expf(-fmaxf(dhC*wv.z + bv.z, 0.f));
        g4[3] = __expf(-fmaxf(dhC*wv.w + bv.w, 0.f));
        #pragma unroll
        for (int L = 0; L < 3; ++L)
          #pragma unroll
          for (int e = 0; e < 4; ++e) hS[L][G][e] *= g4[e];
      }
    }
    #pragma unroll
    for (int G = 0; G < 2; ++G){
      const int d = (w + 4*G)*16 + 4*q;
      fragW4(bufA, d, r, hS[0][G]);
      fragW4(bufB, d, r, hS[1][G]);
      fragW4(bufC, d, r, hS[2][G]);
    }
    // x1 imputation
    {
      float xi[4];
      if (t == 0){ xi[0]=xC.x; xi[1]=xC.y; xi[2]=xC.z; xi[3]=xC.w; }
      else {
        const float* xc = (const float*)&xC; const float* xp = (const float*)&xP;
        const float* x0e = (const float*)&x0v; const float* me = (const float*)&mC;
        #pragma unroll
        for (int e = 0; e < 4; ++e){
          const float gx = __expf(-fmaxf(dxC*Wdx4[e] + bdx4[e], 0.f));
          xi[e] = (xp[e]*gx + (1.f-gx)*x0e[e])*(1.f-me[e]) + me[e]*xc[e];
        }
      }
      fragW4(bufX, v0, bx, xi);
    }
    barrier_lds();   // B0

    if (t >= 1 && tid < 16){
      float l0 = bo[0], l1 = bo[1], l2 = bo[2], l3 = bo[3];
      #pragma unroll
      for (int wv = 0; wv < 4; ++wv){
        const float4 o = *(const float4*)&headBuf[wv][tid][0];
        l0 += o.x; l1 += o.y; l2 += o.z; l3 += o.w;
      }
      const float mx = fmaxf(fmaxf(l0,l1), fmaxf(l2,l3));
      const float e0 = __expf(l0-mx), e1 = __expf(l1-mx), e2 = __expf(l2-mx), e3 = __expf(l3-mx);
      const float inv = 1.f/(e0+e1+e2+e3);
      float4 o; o.x = e0*inv; o.y = e1*inv; o.z = e2*inv; o.w = e3*inv;
      *(float4*)(y + ((size_t)(b0 + tid)*TT + (t-1))*4) = o;
    }

    // ================= P1 =================
    {
      f16x8 bh[4], bx1[2];
      #pragma unroll
      for (int kt = 0; kt < 4; ++kt) bh[kt] = bufA[kt*64 + lane];
      bx1[0] = bufX[lane]; bx1[1] = bufX[64 + lane];
      f32x4v aR[2], aZ[2], aNi[2], aNh[2];
      #pragma unroll
      for (int G = 0; G < 2; ++G){
        const int d = (w + 4*G)*16 + 4*q;
        aR[G]  = *(const f32x4v*)&sBias[0][0][d];
        aZ[G]  = *(const f32x4v*)&sBias[0][1][d];
        aNi[G] = *(const f32x4v*)&sBias[0][2][d];
        aNh[G] = *(const f32x4v*)&sBias[0][3][d];
      }
      #pragma unroll
      for (int G = 0; G < 2; ++G)
        #pragma unroll
        for (int kt = 0; kt < 4; ++kt){
          aR[G]  = MFMA(Ahh[0][G][0][kt], bh[kt], aR[G]);
          aZ[G]  = MFMA(Ahh[0][G][1][kt], bh[kt], aZ[G]);
          aNh[G] = MFMA(Ahh[0][G][2][kt], bh[kt], aNh[G]);
        }
      // issue ih2-G0 (used in P2)
      #pragma unroll
      for (int g = 0; g < 3; ++g)
        #pragma unroll
        for (int kt = 0; kt < 4; ++kt) AiA[g][kt] = ldws4(ws, WS_IH2, g*8 + w, kt, lane);
      #pragma unroll
      for (int G = 0; G < 2; ++G)
        #pragma unroll
        for (int kt = 0; kt < 2; ++kt){
          aR[G]  = MFMA(Ai1[G][0][kt], bx1[kt], aR[G]);
          aZ[G]  = MFMA(Ai1[G][1][kt], bx1[kt], aZ[G]);
          aNi[G] = MFMA(Ai1[G][2][kt], bx1[kt], aNi[G]);
        }
      #pragma unroll
      for (int G = 0; G < 2; ++G){
        gates4(aR[G], aZ[G], aNi[G], aNh[G], hS[0][G]);
        fragW4(bufD, (w + 4*G)*16 + 4*q, r, hS[0][G]);
      }
    }
    barrier_lds();   // B1

    // ================= P2 =================
    {
      f16x8 bh[4], bf[4];
      #pragma unroll
      for (int kt = 0; kt < 4; ++kt){ bh[kt] = bufB[kt*64 + lane]; bf[kt] = bufD[kt*64 + lane]; }
      // issue ih2-G1
      #pragma unroll
      for (int g = 0; g < 3; ++g)
        #pragma unroll
        for (int kt = 0; kt < 4; ++kt) AiB[g][kt] = ldws4(ws, WS_IH2, g*8 + w + 4, kt, lane);
      f32x4v aR[2], aZ[2], aNi[2], aNh[2];
      #pragma unroll
      for (int G = 0; G < 2; ++G){
        const int d = (w + 4*G)*16 + 4*q;
        aR[G]  = *(const f32x4v*)&sBias[1][0][d];
        aZ[G]  = *(const f32x4v*)&sBias[1][1][d];
        aNi[G] = *(const f32x4v*)&sBias[1][2][d];
        aNh[G] = *(const f32x4v*)&sBias[1][3][d];
      }
      #pragma unroll
      for (int G = 0; G < 2; ++G)
        #pragma unroll
        for (int kt = 0; kt < 4; ++kt){
          aR[G]  = MFMA(Ahh[1][G][0][kt], bh[kt], aR[G]);
          aZ[G]  = MFMA(Ahh[1][G][1][kt], bh[kt], aZ[G]);
          aNh[G] = MFMA(Ahh[1][G][2][kt], bh[kt], aNh[G]);
        }
      #pragma unroll
      for (int kt = 0; kt < 4; ++kt){
        aR[0]  = MFMA(AiA[0][kt], bf[kt], aR[0]);
        aZ[0]  = MFMA(AiA[1][kt], bf[kt], aZ[0]);
        aNi[0] = MFMA(AiA[2][kt], bf[kt], aNi[0]);
      }
      #pragma unroll
      for (int kt = 0; kt < 4; ++kt){
        aR[1]  = MFMA(AiB[0][kt], bf[kt], aR[1]);
        aZ[1]  = MFMA(AiB[1][kt], bf[kt], aZ[1]);
        aNi[1] = MFMA(AiB[2][kt], bf[kt], aNi[1]);
      }
      // issue ih3-G0 (reuse AiA)
      #pragma unroll
      for (int g = 0; g < 3; ++g)
        #pragma unroll
        for (int kt = 0; kt < 4; ++kt) AiA[g][kt] = ldws4(ws, WS_IH3, g*8 + w, kt, lane);
      #pragma unroll
      for (int G = 0; G < 2; ++G){
        gates4(aR[G], aZ[G], aNi[G], aNh[G], hS[1][G]);
        fragW4(bufE, (w + 4*G)*16 + 4*q, r, hS[1][G]);
      }
    }
    barrier_lds();   // B2

    // ================= P3 =================
    {
      f16x8 bh[4], bf[4];
      #pragma unroll
      for (int kt = 0; kt < 4; ++kt){ bh[kt] = bufC[kt*64 + lane]; bf[kt] = bufE[kt*64 + lane]; }
      // issue ih3-G1 (reuse AiB)
      #pragma unroll
      for (int g = 0; g < 3; ++g)
        #pragma unroll
        for (int kt = 0; kt < 4; ++kt) AiB[g][kt] = ldws4(ws, WS_IH3, g*8 + w + 4, kt, lane);
      f32x4v aR[2], aZ[2], aNi[2], aNh[2];
      #pragma unroll
      for (int G = 0; G < 2; ++G){
        const int d = (w + 4*G)*16 + 4*q;
        aR[G]  = *(const f32x4v*)&sBias[2][0][d];
        aZ[G]  = *(const f32x4v*)&sBias[2][1][d];
        aNi[G] = *(const f32x4v*)&sBias[2][2][d];
        aNh[G] = *(const f32x4v*)&sBias[2][3][d];
      }
      #pragma unroll
      for (int G = 0; G < 2; ++G)
        #pragma unroll
        for (int kt = 0; kt < 4; ++kt){
          aR[G]  = MFMA(Ahh[2][G][0][kt], bh[kt], aR[G]);
          aZ[G]  = MFMA(Ahh[2][G][1][kt], bh[kt], aZ[G]);
          aNh[G] = MFMA(Ahh[2][G][2][kt], bh[kt], aNh[G]);
        }
      #pragma unroll
      for (int kt = 0; kt < 4; ++kt){
        aR[0]  = MFMA(AiA[0][kt], bf[kt], aR[0]);
        aZ[0]  = MFMA(AiA[1][kt], bf[kt], aZ[0]);
        aNi[0] = MFMA(AiA[2][kt], bf[kt], aNi[0]);
      }
      #pragma unroll
      for (int kt = 0; kt < 4; ++kt){
        aR[1]  = MFMA(AiB[0][kt], bf[kt], aR[1]);
        aZ[1]  = MFMA(AiB[1][kt], bf[kt], aZ[1]);
        aNi[1] = MFMA(AiB[2][kt], bf[kt], aNi[1]);
      }
      // issue ih1 for t+1
      #pragma unroll
      for (int G = 0; G < 2; ++G)
        #pragma unroll
        for (int g = 0; g < 3; ++g)
          #pragma unroll
          for (int kt = 0; kt < 2; ++kt)
            Ai1[G][g][kt] = ldws2(ws, WS_IH1, g*8 + w + 4*G, kt, lane);
      #pragma unroll
      for (int G = 0; G < 2; ++G)
        gates4(aR[G], aZ[G], aNi[G], aNh[G], hS[2][G]);
    }

    // rotate + prefetch x/m/d (t+2)
    xP = xC; xC = xN; mC = mN; dhC = dhN; dxC = dxN;
    {
      const int tp = (t + 2 < TT) ? (t + 2) : (TT - 1);
      xN  = ld4(x  + ((size_t)(b0 + bx)*TT + tp)*VV + v0);
      mN  = ld4(m1 + ((size_t)(b0 + bx)*TT + tp)*VV + v0);
      dxN = dd[(size_t)(b0 + bx)*TT + tp];
      dhN = dd[(size_t)(b0 + r)*TT + tp];
    }
    barrier_lds();   // B3 (protects bufA..E/X/headBuf reuse)
  }

  // ================= epilogue: y[TT-1] =================
  {
    float p[4] = {0.f, 0.f, 0.f, 0.f};
    #pragma unroll
    for (int G = 0; G < 2; ++G)
      #pragma unroll
      for (int e = 0; e < 4; ++e){
        const int d = (w + 4*G)*16 + 4*q + e;
        const float hv = hS[2][G][e];
        #pragma unroll
        for (int c = 0; c < 4; ++c) p[c] += hv * (float)sWout[d][c];
      }
    #pragma unroll
    for (int c = 0; c < 4; ++c){
      p[c] += __shfl_xor(p[c], 16);
      p[c] += __shfl_xor(p[c], 32);
    }
    if (q == 0){
      float4 o; o.x = p[0]; o.y = p[1]; o.z = p[2]; o.w = p[3];
      *(float4*)&headBuf[w][r][0] = o;
    }
    __syncthreads();
    if (tid < 16){
      float l0 = bo[0], l1 = bo[1], l2 = bo[2], l3 = bo[3];
      #pragma unroll
      for (int wv = 0; wv < 4; ++wv){
        const float4 o = *(const float4*)&headBuf[wv][tid][0];
        l0 += o.x; l1 += o.y; l2 += o.z; l3 += o.w;
      }
      const float mx = fmaxf(fmaxf(l0,l1), fmaxf(l2,l3));
      const float e0 = __expf(l0-mx), e1 = __expf(l1-mx), e2 = __expf(l2-mx), e3 = __expf(l3-mx);
      const float inv = 1.f/(e0+e1+e2+e3);
      float4 o; o.x = e0*inv; o.y = e1*inv; o.z = e2*inv; o.w = e3*inv;
      *(float4*)(y + ((size_t)(b0 + tid)*TT + (TT-1))*4) = o;
    }
  }
}

extern "C" void kernel_launch(void* const* d_in, const int* in_sizes, int n_in,
                              void* d_out, int out_size, void* d_ws, size_t ws_size,
                              hipStream_t stream) {
  (void)in_sizes; (void)n_in; (void)out_size; (void)ws_size;
  char* ws = (char*)d_ws;
  k_init<<<dim3(132), dim3(256), 0, stream>>>(
      (const float*)d_in[6],  (const float*)d_in[7],   // Wih1, Whh1
      (const float*)d_in[10], (const float*)d_in[11],  // Wih2, Whh2
      (const float*)d_in[14], (const float*)d_in[15],  // Wih3, Whh3
      ws);
  k_main<<<dim3(32), dim3(256), 0, stream>>>(
      (const float*)d_in[0],  (const float*)d_in[1],  (const float*)d_in[2],   // x, d, m1
      (const float*)d_in[3],  (const float*)d_in[4],  (const float*)d_in[5],   // h0_1..3
      (const float*)d_in[8],  (const float*)d_in[9],                           // bih1, bhh1
      (const float*)d_in[12], (const float*)d_in[13],                          // bih2, bhh2
      (const float*)d_in[16], (const float*)d_in[17],                          // bih3, bhh3
      (const float*)d_in[20], (const float*)d_in[21],                          // W_dx, b_dx
      (const float*)d_in[22], (const float*)d_in[23],                          // W_dh, b_dh
      (const float*)d_in[18], (const float*)d_in[19],                          // W_out, b_out
      (float*)d_out, ws);
}

// Round 6
// 3660.206 us; speedup vs baseline: 1.8906x; 1.6486x over previous
//
#include <hip/hip_runtime.h>

#define TT 512
#define VV 64

typedef _Float16 f16;
typedef f16 f16x8 __attribute__((ext_vector_type(8)));
typedef f16 f16x4 __attribute__((ext_vector_type(4)));
typedef f16 f16x2 __attribute__((ext_vector_type(2)));
typedef float f32x4v __attribute__((ext_vector_type(4)));

#define MFMA(A_,B_,C_) __builtin_amdgcn_mfma_f32_16x16x32_f16((A_),(B_),(C_),0,0,0)

// ws layout (bytes) — f16 MFMA A-fragments packed by k_init
#define WS_IH1 0u
#define WS_HH1 49152u
#define WS_IH2 147456u
#define WS_HH2 245760u
#define WS_IH3 344064u
#define WS_HH3 442368u

__device__ __forceinline__ void barrier_lds(){ asm volatile("s_waitcnt lgkmcnt(0)\n\ts_barrier" ::: "memory"); }

__device__ __forceinline__ int fragOff16(int d0, int b){
  const int kt = d0 >> 5, qq = (d0 >> 3) & 3, j0 = d0 & 7;
  return (kt*64 + qq*16 + b)*8 + j0;
}
__device__ __forceinline__ void fragW4(f16x8* buf, int d0, int b, const float* h4){
  f16x4 v;
  #pragma unroll
  for (int e = 0; e < 4; ++e) v[e] = (f16)h4[e];
  *(f16x4*)((f16*)buf + fragOff16(d0, b)) = v;
}
__device__ __forceinline__ void fragW2(f16x8* buf, int v0, int b, float a0, float a1){
  f16x2 v; v[0] = (f16)a0; v[1] = (f16)a1;
  *(f16x2*)((f16*)buf + fragOff16(v0, b)) = v;
}
__device__ __forceinline__ float sigm(float v){ return 1.f/(1.f + __expf(-v)); }
__device__ __forceinline__ float4 ld4(const float* p){ return *(const float4*)p; }

__device__ __forceinline__ f16x8 ldws4(const char* ws, unsigned off, int m, int kt, int lane){
  return *(const f16x8*)(ws + off + (((size_t)(m*4 + kt))*64 + lane)*16);
}
__device__ __forceinline__ f16x8 ldws2(const char* ws, unsigned off, int m, int kt, int lane){
  return *(const f16x8*)(ws + off + (((size_t)(m*2 + kt))*64 + lane)*16);
}

__device__ __forceinline__ void gates4(const f32x4v aR, const f32x4v aZ,
                                       const f32x4v aNi, const f32x4v aNh, float* hp){
  #pragma unroll
  for (int e = 0; e < 4; ++e){
    const float rr = sigm(aR[e]);
    const float zz = sigm(aZ[e]);
    const float nv = aNi[e] + rr*aNh[e];
    const float nn = 1.f - 2.f/(1.f + __expf(2.f*nv));
    hp[e] = (1.f - zz)*nn + zz*hp[e];
  }
}

// ---------------- k_init: pack weights into f16 A-fragments ----------------
__global__ void k_init(const float* __restrict__ Wih1, const float* __restrict__ Whh1,
                       const float* __restrict__ Wih2, const float* __restrict__ Whh2,
                       const float* __restrict__ Wih3, const float* __restrict__ Whh3,
                       char* __restrict__ ws)
{
  const int n = blockIdx.x*256 + threadIdx.x;
  if (n >= 33792) return;
  const float* W; int KF; unsigned off; int i = n;
  if (i < 3072){ W = Wih1; KF = 2; off = WS_IH1; }
  else {
    i -= 3072; const int mi = i/6144; i %= 6144;
    const float* Ws[5] = {Whh1, Wih2, Whh2, Wih3, Whh3};
    const unsigned offs[5] = {WS_HH1, WS_IH2, WS_HH2, WS_IH3, WS_HH3};
    W = Ws[mi]; off = offs[mi]; KF = 4;
  }
  const int l = i & 63; i >>= 6; const int kt = i % KF; const int m = i / KF;
  const int K = KF*32;
  const float* src = W + (size_t)(m*16 + (l & 15))*K + kt*32 + ((l >> 4) & 3)*8;
  f16x8 v;
  #pragma unroll
  for (int j = 0; j < 8; ++j) v[j] = (f16)src[j];
  *(f16x8*)(ws + off + ((size_t)(m*KF + kt)*64 + l)*16) = v;
}

// ---------------- k_main: fused 3-layer GRU-D, 8 waves, all weights streamed ----------------
__launch_bounds__(512, 2)
__global__ void k_main(const float* __restrict__ x,  const float* __restrict__ dd,
                       const float* __restrict__ m1,
                       const float* __restrict__ h01, const float* __restrict__ h02,
                       const float* __restrict__ h03,
                       const float* __restrict__ bih1, const float* __restrict__ bhh1,
                       const float* __restrict__ bih2, const float* __restrict__ bhh2,
                       const float* __restrict__ bih3, const float* __restrict__ bhh3,
                       const float* __restrict__ Wdx_, const float* __restrict__ bdx_,
                       const float* __restrict__ Wdh_, const float* __restrict__ bdh_,
                       const float* __restrict__ Wout, const float* __restrict__ bout,
                       float* __restrict__ y, const char* __restrict__ ws)
{
  __shared__ f16x8 bufA[256];   // γh1
  __shared__ f16x8 bufB[256];   // γh2
  __shared__ f16x8 bufC[256];   // γh3
  __shared__ f16x8 bufD[256];   // h1 fresh
  __shared__ f16x8 bufE[256];   // h2 fresh
  __shared__ f16x8 bufX[128];   // x1
  __shared__ float sBias[3][4][128];   // [L][r,z,bI,bH][d]
  __shared__ float sWdh[128], sbdh[128];
  __shared__ float4 sWoutF[128];
  __shared__ float headBuf[8][16][4];

  const int tid = threadIdx.x, w = tid >> 6, lane = tid & 63;
  const int q = lane >> 4, r = lane & 15;
  const int b0 = blockIdx.x * 16;
  const int dG = w*16 + 4*q;           // this wave's d-tile base + quad offset

  if (tid < 128){
    const float* bis[3] = {bih1, bih2, bih3};
    const float* bhs[3] = {bhh1, bhh2, bhh3};
    #pragma unroll
    for (int L = 0; L < 3; ++L){
      sBias[L][0][tid] = bis[L][tid]       + bhs[L][tid];
      sBias[L][1][tid] = bis[L][128 + tid] + bhs[L][128 + tid];
      sBias[L][2][tid] = bis[L][256 + tid];
      sBias[L][3][tid] = bhs[L][256 + tid];
    }
    sWdh[tid] = Wdh_[tid]; sbdh[tid] = bdh_[tid];
    float4 wo; wo.x = Wout[tid]; wo.y = Wout[128+tid]; wo.z = Wout[256+tid]; wo.w = Wout[384+tid];
    sWoutF[tid] = wo;
  }
  float bo[4];
  if (tid < 16){
    #pragma unroll
    for (int c = 0; c < 4; ++c) bo[c] = bout[c];
  }

  // h state for this wave's d-tile (col=batch=r, rows dG..dG+3)
  float hS1[4], hS2[4], hS3[4];
  {
    float4 a;
    a = ld4(h01 + (size_t)(b0 + r)*128 + dG); hS1[0]=a.x; hS1[1]=a.y; hS1[2]=a.z; hS1[3]=a.w;
    a = ld4(h02 + (size_t)(b0 + r)*128 + dG); hS2[0]=a.x; hS2[1]=a.y; hS2[2]=a.z; hS2[3]=a.w;
    a = ld4(h03 + (size_t)(b0 + r)*128 + dG); hS3[0]=a.x; hS3[1]=a.y; hS3[2]=a.z; hS3[3]=a.w;
  }

  // x-path: 512 lanes cover 16 batches x 64 V at 2 values/lane
  const int bx = tid >> 5, v0 = (tid & 31)*2;
  const float wdx0 = Wdx_[v0], wdx1 = Wdx_[v0+1];
  const float bdx0 = bdx_[v0], bdx1 = bdx_[v0+1];
  float xc0, xc1, x00, x01, xp0, xp1, mc0 = 0.f, mc1 = 0.f, xn0, xn1, mn0, mn1;
  float dxC = 0.f, dhC = 0.f, dxN, dhN;
  {
    const float* px = x + ((size_t)(b0 + bx)*TT + 0)*VV + v0;
    xc0 = px[0]; xc1 = px[1]; x00 = xc0; x01 = xc1; xp0 = xc0; xp1 = xc1;
    const float* pn = x + ((size_t)(b0 + bx)*TT + 1)*VV + v0;
    xn0 = pn[0]; xn1 = pn[1];
    const float* pm = m1 + ((size_t)(b0 + bx)*TT + 1)*VV + v0;
    mn0 = pm[0]; mn1 = pm[1];
    dxN = dd[(size_t)(b0 + bx)*TT + 1];
    dhN = dd[(size_t)(b0 + r)*TT + 1];
  }

  // streamed weight double-buffers (48 VGPRs each)
  f16x8 U[12], V[12];
  #pragma unroll
  for (int g = 0; g < 3; ++g){
    #pragma unroll
    for (int kt = 0; kt < 4; ++kt) U[g*4+kt] = ldws4(ws, WS_HH1, g*8 + w, kt, lane);
    #pragma unroll
    for (int kt = 0; kt < 2; ++kt) V[g*2+kt] = ldws2(ws, WS_IH1, g*8 + w, kt, lane);
  }

  __syncthreads();

  for (int t = 0; t < TT; ++t){
    // ================= B0: head partial, decay, pack frags =================
    if (t >= 1){
      // head partial from fresh h3(t-1), BEFORE decay
      float p[4] = {0.f, 0.f, 0.f, 0.f};
      #pragma unroll
      for (int e = 0; e < 4; ++e){
        const float4 wo = sWoutF[dG + e];
        const float hv = hS3[e];
        p[0] += hv*wo.x; p[1] += hv*wo.y; p[2] += hv*wo.z; p[3] += hv*wo.w;
      }
      #pragma unroll
      for (int c = 0; c < 4; ++c){
        p[c] += __shfl_xor(p[c], 16);
        p[c] += __shfl_xor(p[c], 32);
      }
      if (q == 0){
        float4 o; o.x = p[0]; o.y = p[1]; o.z = p[2]; o.w = p[3];
        *(float4*)&headBuf[w][r][0] = o;
      }
      // decay (params from LDS)
      const float4 wv = *(const float4*)&sWdh[dG];
      const float4 bv = *(const float4*)&sbdh[dG];
      float g4[4];
      g4[0] = __expf(-fmaxf(dhC*wv.x + bv.x, 0.f));
      g4[1] = __expf(-fmaxf(dhC*wv.y + bv.y, 0.f));
      g4[2] = __expf(-fmaxf(dhC*wv.z + bv.z, 0.f));
      g4[3] = __expf(-fmaxf(dhC*wv.w + bv.w, 0.f));
      #pragma unroll
      for (int e = 0; e < 4; ++e){ hS1[e] *= g4[e]; hS2[e] *= g4[e]; hS3[e] *= g4[e]; }
    }
    fragW4(bufA, dG, r, hS1);
    fragW4(bufB, dG, r, hS2);
    fragW4(bufC, dG, r, hS3);
    // x1 imputation (2 values/lane)
    {
      float xi0, xi1;
      if (t == 0){ xi0 = xc0; xi1 = xc1; }
      else {
        const float gx0 = __expf(-fmaxf(dxC*wdx0 + bdx0, 0.f));
        const float gx1 = __expf(-fmaxf(dxC*wdx1 + bdx1, 0.f));
        xi0 = (xp0*gx0 + (1.f-gx0)*x00)*(1.f-mc0) + mc0*xc0;
        xi1 = (xp1*gx1 + (1.f-gx1)*x01)*(1.f-mc1) + mc1*xc1;
      }
      fragW2(bufX, v0, bx, xi0, xi1);
    }
    barrier_lds();   // B0

    // head finalize for t-1 (wave 0, lanes 0..15)
    if (t >= 1 && tid < 16){
      float l0 = bo[0], l1 = bo[1], l2 = bo[2], l3 = bo[3];
      #pragma unroll
      for (int wv = 0; wv < 8; ++wv){
        const float4 o = *(const float4*)&headBuf[wv][tid][0];
        l0 += o.x; l1 += o.y; l2 += o.z; l3 += o.w;
      }
      const float mx = fmaxf(fmaxf(l0,l1), fmaxf(l2,l3));
      const float e0 = __expf(l0-mx), e1 = __expf(l1-mx), e2 = __expf(l2-mx), e3 = __expf(l3-mx);
      const float inv = 1.f/(e0+e1+e2+e3);
      float4 o; o.x = e0*inv; o.y = e1*inv; o.z = e2*inv; o.w = e3*inv;
      *(float4*)(y + ((size_t)(b0 + tid)*TT + (t-1))*4) = o;
    }

    // ================= P1: layer 1 =================
    {
      f16x8 bh[4];
      #pragma unroll
      for (int kt = 0; kt < 4; ++kt) bh[kt] = bufA[kt*64 + lane];
      f16x8 bx1[2]; bx1[0] = bufX[lane]; bx1[1] = bufX[64 + lane];
      f32x4v aR  = *(const f32x4v*)&sBias[0][0][dG];
      f32x4v aZ  = *(const f32x4v*)&sBias[0][1][dG];
      f32x4v aNi = *(const f32x4v*)&sBias[0][2][dG];
      f32x4v aNh = *(const f32x4v*)&sBias[0][3][dG];
      #pragma unroll
      for (int kt = 0; kt < 4; ++kt){
        aR  = MFMA(U[kt],   bh[kt], aR);
        aZ  = MFMA(U[4+kt], bh[kt], aZ);
        aNh = MFMA(U[8+kt], bh[kt], aNh);
      }
      // U free -> issue hh2 (consumed at P2 start)
      #pragma unroll
      for (int g = 0; g < 3; ++g)
        #pragma unroll
        for (int kt = 0; kt < 4; ++kt) U[g*4+kt] = ldws4(ws, WS_HH2, g*8 + w, kt, lane);
      #pragma unroll
      for (int kt = 0; kt < 2; ++kt){
        aR  = MFMA(V[kt],   bx1[kt], aR);
        aZ  = MFMA(V[2+kt], bx1[kt], aZ);
        aNi = MFMA(V[4+kt], bx1[kt], aNi);
      }
      // V free -> issue ih2 (consumed at P2 end)
      #pragma unroll
      for (int g = 0; g < 3; ++g)
        #pragma unroll
        for (int kt = 0; kt < 4; ++kt) V[g*4+kt] = ldws4(ws, WS_IH2, g*8 + w, kt, lane);
      gates4(aR, aZ, aNi, aNh, hS1);
      fragW4(bufD, dG, r, hS1);
    }
    barrier_lds();   // B1

    // ================= P2: layer 2 =================
    {
      f16x8 bh[4], bf[4];
      #pragma unroll
      for (int kt = 0; kt < 4; ++kt){ bh[kt] = bufB[kt*64 + lane]; bf[kt] = bufD[kt*64 + lane]; }
      f32x4v aR  = *(const f32x4v*)&sBias[1][0][dG];
      f32x4v aZ  = *(const f32x4v*)&sBias[1][1][dG];
      f32x4v aNi = *(const f32x4v*)&sBias[1][2][dG];
      f32x4v aNh = *(const f32x4v*)&sBias[1][3][dG];
      #pragma unroll
      for (int kt = 0; kt < 4; ++kt){
        aR  = MFMA(U[kt],   bh[kt], aR);
        aZ  = MFMA(U[4+kt], bh[kt], aZ);
        aNh = MFMA(U[8+kt], bh[kt], aNh);
      }
      // U free -> issue hh3
      #pragma unroll
      for (int g = 0; g < 3; ++g)
        #pragma unroll
        for (int kt = 0; kt < 4; ++kt) U[g*4+kt] = ldws4(ws, WS_HH3, g*8 + w, kt, lane);
      #pragma unroll
      for (int kt = 0; kt < 4; ++kt){
        aR  = MFMA(V[kt],   bf[kt], aR);
        aZ  = MFMA(V[4+kt], bf[kt], aZ);
        aNi = MFMA(V[8+kt], bf[kt], aNi);
      }
      // V free -> issue ih3
      #pragma unroll
      for (int g = 0; g < 3; ++g)
        #pragma unroll
        for (int kt = 0; kt < 4; ++kt) V[g*4+kt] = ldws4(ws, WS_IH3, g*8 + w, kt, lane);
      gates4(aR, aZ, aNi, aNh, hS2);
      fragW4(bufE, dG, r, hS2);
    }
    barrier_lds();   // B2

    // ================= P3: layer 3 =================
    {
      f16x8 bh[4], bf[4];
      #pragma unroll
      for (int kt = 0; kt < 4; ++kt){ bh[kt] = bufC[kt*64 + lane]; bf[kt] = bufE[kt*64 + lane]; }
      f32x4v aR  = *(const f32x4v*)&sBias[2][0][dG];
      f32x4v aZ  = *(const f32x4v*)&sBias[2][1][dG];
      f32x4v aNi = *(const f32x4v*)&sBias[2][2][dG];
      f32x4v aNh = *(const f32x4v*)&sBias[2][3][dG];
      #pragma unroll
      for (int kt = 0; kt < 4; ++kt){
        aR  = MFMA(U[kt],   bh[kt], aR);
        aZ  = MFMA(U[4+kt], bh[kt], aZ);
        aNh = MFMA(U[8+kt], bh[kt], aNh);
      }
      // U free -> issue hh1 for t+1
      #pragma unroll
      for (int g = 0; g < 3; ++g)
        #pragma unroll
        for (int kt = 0; kt < 4; ++kt) U[g*4+kt] = ldws4(ws, WS_HH1, g*8 + w, kt, lane);
      #pragma unroll
      for (int kt = 0; kt < 4; ++kt){
        aR  = MFMA(V[kt],   bf[kt], aR);
        aZ  = MFMA(V[4+kt], bf[kt], aZ);
        aNi = MFMA(V[8+kt], bf[kt], aNi);
      }
      // V free -> issue ih1 for t+1
      #pragma unroll
      for (int g = 0; g < 3; ++g)
        #pragma unroll
        for (int kt = 0; kt < 2; ++kt) V[g*2+kt] = ldws2(ws, WS_IH1, g*8 + w, kt, lane);
      gates4(aR, aZ, aNi, aNh, hS3);
    }

    // rotate + prefetch x/m/d (t+2)
    xp0 = xc0; xp1 = xc1; xc0 = xn0; xc1 = xn1;
    mc0 = mn0; mc1 = mn1; dhC = dhN; dxC = dxN;
    {
      const int tp = (t + 2 < TT) ? (t + 2) : (TT - 1);
      const float* pn = x + ((size_t)(b0 + bx)*TT + tp)*VV + v0;
      xn0 = pn[0]; xn1 = pn[1];
      const float* pm = m1 + ((size_t)(b0 + bx)*TT + tp)*VV + v0;
      mn0 = pm[0]; mn1 = pm[1];
      dxN = dd[(size_t)(b0 + bx)*TT + tp];
      dhN = dd[(size_t)(b0 + r)*TT + tp];
    }
    barrier_lds();   // B3 (frag buffers reused next B0)
  }

  // ================= epilogue: y[TT-1] =================
  {
    float p[4] = {0.f, 0.f, 0.f, 0.f};
    #pragma unroll
    for (int e = 0; e < 4; ++e){
      const float4 wo = sWoutF[dG + e];
      const float hv = hS3[e];
      p[0] += hv*wo.x; p[1] += hv*wo.y; p[2] += hv*wo.z; p[3] += hv*wo.w;
    }
    #pragma unroll
    for (int c = 0; c < 4; ++c){
      p[c] += __shfl_xor(p[c], 16);
      p[c] += __shfl_xor(p[c], 32);
    }
    if (q == 0){
      float4 o; o.x = p[0]; o.y = p[1]; o.z = p[2]; o.w = p[3];
      *(float4*)&headBuf[w][r][0] = o;
    }
    barrier_lds();
    if (tid < 16){
      float l0 = bo[0], l1 = bo[1], l2 = bo[2], l3 = bo[3];
      #pragma unroll
      for (int wv = 0; wv < 8; ++wv){
        const float4 o = *(const float4*)&headBuf[wv][tid][0];
        l0 += o.x; l1 += o.y; l2 += o.z; l3 += o.w;
      }
      const float mx = fmaxf(fmaxf(l0,l1), fmaxf(l2,l3));
      const float e0 = __expf(l0-mx), e1 = __expf(l1-mx), e2 = __expf(l2-mx), e3 = __expf(l3-mx);
      const float inv = 1.f/(e0+e1+e2+e3);
      float4 o; o.x = e0*inv; o.y = e1*inv; o.z = e2*inv; o.w = e3*inv;
      *(float4*)(y + ((size_t)(b0 + tid)*TT + (TT-1))*4) = o;
    }
  }
}

extern "C" void kernel_launch(void* const* d_in, const int* in_sizes, int n_in,
                              void* d_out, int out_size, void* d_ws, size_t ws_size,
                              hipStream_t stream) {
  (void)in_sizes; (void)n_in; (void)out_size; (void)ws_size;
  char* ws = (char*)d_ws;
  k_init<<<dim3(132), dim3(256), 0, stream>>>(
      (const float*)d_in[6],  (const float*)d_in[7],   // Wih1, Whh1
      (const float*)d_in[10], (const float*)d_in[11],  // Wih2, Whh2
      (const float*)d_in[14], (const float*)d_in[15],  // Wih3, Whh3
      ws);
  k_main<<<dim3(32), dim3(512), 0, stream>>>(
      (const float*)d_in[0],  (const float*)d_in[1],  (const float*)d_in[2],   // x, d, m1
      (const float*)d_in[3],  (const float*)d_in[4],  (const float*)d_in[5],   // h0_1..3
      (const float*)d_in[8],  (const float*)d_in[9],                           // bih1, bhh1
      (const float*)d_in[12], (const float*)d_in[13],                          // bih2, bhh2
      (const float*)d_in[16], (const float*)d_in[17],                          // bih3, bhh3
      (const float*)d_in[20], (const float*)d_in[21],                          // W_dx, b_dx
      (const float*)d_in[22], (const float*)d_in[23],                          // W_dh, b_dh
      (const float*)d_in[18], (const float*)d_in[19],                          // W_out, b_out
      (float*)d_out, ws);
}